// Round 9
// baseline (677.039 us; speedup 1.0000x reference)
//
#include <hip/hip_runtime.h>
#include <math.h>

#define L_DIM 2048
#define N_DIM 8
#define E_DIM 1024
#define H_DIM 16
#define D_DIM 64
#define M_DIM (L_DIM * N_DIM)     // 16384
#define NHEADS (N_DIM * H_DIM)    // 128
#define TWO_D 128
#define K_DIM 1024
#define CH 4                      // L-chunks for kv partials
#define LCH (L_DIM / CH)          // 512

#define KV_ELEMS (NHEADS * TWO_D * D_DIM)   // 1048576
#define KS_ELEMS (NHEADS * TWO_D)           // 16384
#define CSTRIDE (KV_ELEMS + KS_ELEMS)       // 1064960 floats per chunk

typedef __attribute__((ext_vector_type(8))) __bf16 bf16x8;
typedef __attribute__((ext_vector_type(4))) float f32x4;

__device__ __forceinline__ ushort f2bf(float x) {
    union { float f; unsigned u; } a; a.f = x;
    unsigned r = a.u + 0x7fffu + ((a.u >> 16) & 1u);
    return (ushort)(r >> 16);
}
__device__ __forceinline__ float bf2f(ushort h) {
    union { unsigned u; float f; } a; a.u = ((unsigned)h) << 16;
    return a.f;
}

__device__ __forceinline__ void gload_lds16(const void* g, void* l) {
    __builtin_amdgcn_global_load_lds((const __attribute__((address_space(1))) void*)g,
                                     (__attribute__((address_space(3))) void*)l, 16, 0, 0);
}

// ---------------------------------------------------------------------------
// split fp32 -> bf16 hi + lo
// ---------------------------------------------------------------------------
__global__ __launch_bounds__(256) void split_fp32(const float* __restrict__ in,
                                                  ushort* __restrict__ hi,
                                                  ushort* __restrict__ lo, int n4) {
    int i = blockIdx.x * 256 + threadIdx.x;
    const int stride = gridDim.x * 256;
    for (; i < n4; i += stride) {
        float4 v = ((const float4*)in)[i];
        ushort h0 = f2bf(v.x), h1 = f2bf(v.y), h2 = f2bf(v.z), h3 = f2bf(v.w);
        ushort l0 = f2bf(v.x - bf2f(h0)), l1 = f2bf(v.y - bf2f(h1));
        ushort l2 = f2bf(v.z - bf2f(h2)), l3 = f2bf(v.w - bf2f(h3));
        ((ushort4*)hi)[i] = make_ushort4(h0, h1, h2, h3);
        ((ushort4*)lo)[i] = make_ushort4(l0, l1, l2, l3);
    }
}

__global__ __launch_bounds__(256) void split_w4(const float* __restrict__ w0,
                                                const float* __restrict__ w1,
                                                const float* __restrict__ w2,
                                                const float* __restrict__ w3,
                                                ushort* __restrict__ hi,
                                                ushort* __restrict__ lo) {
    const int midx = blockIdx.y;
    const float* src = (midx == 0) ? w0 : (midx == 1) ? w1 : (midx == 2) ? w2 : w3;
    hi += (size_t)midx * E_DIM * E_DIM;
    lo += (size_t)midx * E_DIM * E_DIM;
    const int n4 = E_DIM * E_DIM / 4;
    int i = blockIdx.x * 256 + threadIdx.x;
    const int stride = gridDim.x * 256;
    for (; i < n4; i += stride) {
        float4 v = ((const float4*)src)[i];
        ushort h0 = f2bf(v.x), h1 = f2bf(v.y), h2 = f2bf(v.z), h3 = f2bf(v.w);
        ushort l0 = f2bf(v.x - bf2f(h0)), l1 = f2bf(v.y - bf2f(h1));
        ushort l2 = f2bf(v.z - bf2f(h2)), l3 = f2bf(v.w - bf2f(h3));
        ((ushort4*)hi)[i] = make_ushort4(h0, h1, h2, h3);
        ((ushort4*)lo)[i] = make_ushort4(l0, l1, l2, l3);
    }
}

// ---------------------------------------------------------------------------
// split-bf16 MFMA GEMM-NT, 256x256 tile, BK=32, 8 waves (2M x 4N, 128x64/wave).
// mfma_f32_16x16x32_bf16 (conflict-free swizzle, r7-verified).
// A hi/lo: double-buffered LDS (64 KiB). B hi/lo: per-wave REGISTER prefetch
// (T14) double-buffered, loaded direct from global (L2-resident W panels).
// Sync structure identical to r7: STAGE(next)+LOADB(next) -> compute(cur)
// -> __syncthreads. 3 MFMAs per (m,n,k): hi*hi + hi*lo + lo*hi.
// Grid MUST be 64 * NBS blocks (64 M-tiles x NBS N-tiles of 256).
// OUTMODE 0: row-major fp32; 1: head-major+relu (Q); 2: fused K|V head-major.
// ---------------------------------------------------------------------------
__device__ __forceinline__ void loadB(const ushort* __restrict__ bH,
                                      const ushort* __restrict__ bL,
                                      int kt, bf16x8 bh[4], bf16x8 bl[4]) {
    const size_t o = (size_t)kt * 32;
    const size_t RS = (size_t)16 * K_DIM;
#pragma unroll
    for (int n = 0; n < 4; ++n) {
        bh[n] = *(const bf16x8*)(bH + (size_t)n * RS + o);
        bl[n] = *(const bf16x8*)(bL + (size_t)n * RS + o);
    }
}

__device__ __forceinline__ void computeA(const ushort* __restrict__ bb,
                                         const int* aoff,
                                         const bf16x8 bh[4], const bf16x8 bl[4],
                                         f32x4 acc[8][4]) {
#pragma unroll
    for (int m = 0; m < 8; ++m) {
        const bf16x8 ah = *(const bf16x8*)&bb[aoff[m]];
        const bf16x8 al = *(const bf16x8*)&bb[8192 + aoff[m]];
#pragma unroll
        for (int n = 0; n < 4; ++n) {
            acc[m][n] = __builtin_amdgcn_mfma_f32_16x16x32_bf16(ah, bh[n], acc[m][n], 0, 0, 0);
            acc[m][n] = __builtin_amdgcn_mfma_f32_16x16x32_bf16(ah, bl[n], acc[m][n], 0, 0, 0);
            acc[m][n] = __builtin_amdgcn_mfma_f32_16x16x32_bf16(al, bh[n], acc[m][n], 0, 0, 0);
        }
    }
}

template <int OUTMODE, int NBS>
__global__ __launch_bounds__(512, 2) void gemm2(const ushort* __restrict__ Ahi,
                                                const ushort* __restrict__ Alo,
                                                const ushort* __restrict__ Bhi,
                                                const ushort* __restrict__ Blo,
                                                float* __restrict__ C,
                                                float* __restrict__ C2) {
    // buffer (ushorts): A-hi [0,8192), A-lo [8192,16384). 64 KiB total.
    __shared__ ushort smem[2][16384];

    const int t = threadIdx.x;
    const int wid = t >> 6;
    const int lane = t & 63;

    // T1: XCD-grouped decomposition. grid = 64*NBS, 8*NBS blocks per XCD.
    const int x = blockIdx.x;
    const int cxcd = x & 7;
    const int j = x >> 3;                 // 0 .. 8*NBS-1
    const int mb = cxcd * 8 + j / NBS;    // 0..63
    const int nb = j % NBS;
    const int m0 = mb * 256, n0 = nb * 256;

    // ---- A staging source offsets (inverse-swizzled; LDS dest linear) ----
    const int srow = t >> 2;                  // 0..127
    const int sch = t & 3;
    const int gch = sch ^ ((srow >> 1) & 3);  // invariant under row+128
    const size_t aOff = (size_t)(m0 + srow) * K_DIM + gch * 8;
    const size_t H128 = (size_t)128 * K_DIM;

#define STAGE_A(b, kt1)                                           \
    do {                                                          \
        const size_t kc_ = (size_t)(kt1) * 32;                    \
        ushort* d = (ushort*)&smem[b][0] + wid * 512;             \
        gload_lds16(Ahi + aOff + kc_, d);                         \
        gload_lds16(Ahi + aOff + H128 + kc_, d + 4096);           \
        gload_lds16(Alo + aOff + kc_, d + 8192);                  \
        gload_lds16(Alo + aOff + H128 + kc_, d + 12288);          \
    } while (0)

    // ---- A fragment read offsets (swizzled, r7 pattern) ----
    const int wm = wid >> 2;       // 0..1 -> M half (stride 128)
    const int wn = wid & 3;        // 0..3 -> N quarter (stride 64)
    const int lr = lane & 15;
    const int kc = lane >> 4;
    int aoff[8];
#pragma unroll
    for (int m = 0; m < 8; ++m) {
        const int r = wm * 128 + m * 16 + lr;
        aoff[m] = r * 32 + ((kc ^ ((r >> 1) & 3)) << 3);
    }

    // ---- B global source (per-lane direct; no LDS, no swizzle) ----
    const int brow = n0 + wn * 64 + lr;
    const ushort* bH = Bhi + (size_t)brow * K_DIM + kc * 8;
    const ushort* bL = Blo + (size_t)brow * K_DIM + kc * 8;

    f32x4 acc[8][4];
    const f32x4 zv = {0.f, 0.f, 0.f, 0.f};
#pragma unroll
    for (int m = 0; m < 8; ++m)
#pragma unroll
        for (int n = 0; n < 4; ++n) acc[m][n] = zv;

    const int NK = K_DIM / 32;  // 32 (even)

    bf16x8 bhA[4], blA[4], bhB[4], blB[4];
    STAGE_A(0, 0);
    loadB(bH, bL, 0, bhA, blA);
    __syncthreads();

#pragma unroll 1
    for (int kt = 0; kt < NK; kt += 2) {
        // step kt (buf 0, regs A); prefetch kt+1 (always valid: kt <= NK-2)
        STAGE_A(1, kt + 1);
        loadB(bH, bL, kt + 1, bhB, blB);
        computeA(&smem[0][0], aoff, bhA, blA, acc);
        __syncthreads();

        // step kt+1 (buf 1, regs B); prefetch kt+2
        if (kt + 2 < NK) {
            STAGE_A(0, kt + 2);
            loadB(bH, bL, kt + 2, bhA, blA);
        }
        computeA(&smem[1][0], aoff, bhB, blB, acc);
        __syncthreads();
    }

    // ---- epilogue: C/D layout col=lane&15, row=(lane>>4)*4+q ----
    const int erow = (lane >> 4) * 4;
    const int ecol = lane & 15;
#pragma unroll
    for (int m = 0; m < 8; ++m) {
        const int grb = m0 + wm * 128 + m * 16 + erow;
#pragma unroll
        for (int n = 0; n < 4; ++n) {
            const int gc = n0 + wn * 64 + n * 16 + ecol;
            f32x4 v = acc[m][n];
#pragma unroll
            for (int q = 0; q < 4; ++q) {
                const int gr = grb + q;
                float val = v[q];
                if constexpr (OUTMODE == 0) {
                    C[(size_t)gr * E_DIM + gc] = val;
                } else if constexpr (OUTMODE == 1) {
                    val = fmaxf(val, 0.f);
                    const int hh = gc >> 6, d = gc & 63;
                    C[((size_t)((gr & 7) * 16 + hh) * L_DIM + (gr >> 3)) * D_DIM + d] = val;
                } else {
                    const int mat = gc >> 10;  // 0 = K (relu), 1 = V
                    const int col = gc & 1023;
                    if (mat == 0) val = fmaxf(val, 0.f);
                    const int hh = col >> 6, d = col & 63;
                    float* dstc = mat ? C2 : C;
                    dstc[((size_t)((gr & 7) * 16 + hh) * L_DIM + (gr >> 3)) * D_DIM + d] = val;
                }
            }
        }
    }
#undef STAGE_A
}

// ---------------------------------------------------------------------------
// kv partials from head-major K/V (contiguous streams, no atomics)
// ---------------------------------------------------------------------------
__global__ __launch_bounds__(256) void kv_partial(const float* __restrict__ Kh,
                                                  const float* __restrict__ Vh,
                                                  float* __restrict__ kvp) {
    const int g = blockIdx.x;
    const int c = blockIdx.y;
    const int t = threadIdx.x;

    __shared__ float Kt[32][64];
    __shared__ float Vt[32][64];
    __shared__ float sT[32], cT[32];

    const int gi = t >> 3;
    const int gj = t & 7;
    const int i0 = gi * 2, j0 = gj * 8;

    float S[2][8], Cc[2][8];
#pragma unroll
    for (int i = 0; i < 2; ++i)
#pragma unroll
        for (int jj = 0; jj < 8; ++jj) { S[i][jj] = 0.f; Cc[i][jj] = 0.f; }
    float sk[2] = {0.f, 0.f}, ck[2] = {0.f, 0.f};

    for (int lt = 0; lt < LCH; lt += 32) {
        const int lbase = c * LCH + lt;
        const float4* ks = (const float4*)&Kh[((size_t)g * L_DIM + lbase) * D_DIM];
        const float4* vs = (const float4*)&Vh[((size_t)g * L_DIM + lbase) * D_DIM];
        ((float4*)&Kt[0][0])[t] = ks[t];
        ((float4*)&Kt[0][0])[t + 256] = ks[t + 256];
        ((float4*)&Vt[0][0])[t] = vs[t];
        ((float4*)&Vt[0][0])[t + 256] = vs[t + 256];
        if (t < 32) {
            const float ang = 1.57079632679489662f * (float)(lbase + t + 1) / (float)L_DIM;
            sT[t] = sinf(ang);
            cT[t] = cosf(ang);
        }
        __syncthreads();
#pragma unroll 4
        for (int lr = 0; lr < 32; ++lr) {
            const float sl = sT[lr], cl = cT[lr];
            const float k0v = Kt[lr][i0], k1v = Kt[lr][i0 + 1];
            const float ks0 = k0v * sl, ks1 = k1v * sl;
            const float kc0 = k0v * cl, kc1 = k1v * cl;
            sk[0] += ks0; sk[1] += ks1; ck[0] += kc0; ck[1] += kc1;
            float v8[8];
            *(float4*)&v8[0] = *(float4*)&Vt[lr][j0];
            *(float4*)&v8[4] = *(float4*)&Vt[lr][j0 + 4];
#pragma unroll
            for (int jj = 0; jj < 8; ++jj) {
                S[0][jj] = fmaf(ks0, v8[jj], S[0][jj]);
                S[1][jj] = fmaf(ks1, v8[jj], S[1][jj]);
                Cc[0][jj] = fmaf(kc0, v8[jj], Cc[0][jj]);
                Cc[1][jj] = fmaf(kc1, v8[jj], Cc[1][jj]);
            }
        }
        __syncthreads();
    }

    float* kvb = kvp + (size_t)c * CSTRIDE + (size_t)g * TWO_D * D_DIM;
#pragma unroll
    for (int ii = 0; ii < 2; ++ii) {
        *(float4*)&kvb[(size_t)(i0 + ii) * D_DIM + j0] =
            make_float4(S[ii][0], S[ii][1], S[ii][2], S[ii][3]);
        *(float4*)&kvb[(size_t)(i0 + ii) * D_DIM + j0 + 4] =
            make_float4(S[ii][4], S[ii][5], S[ii][6], S[ii][7]);
        *(float4*)&kvb[(size_t)(64 + i0 + ii) * D_DIM + j0] =
            make_float4(Cc[ii][0], Cc[ii][1], Cc[ii][2], Cc[ii][3]);
        *(float4*)&kvb[(size_t)(64 + i0 + ii) * D_DIM + j0 + 4] =
            make_float4(Cc[ii][4], Cc[ii][5], Cc[ii][6], Cc[ii][7]);
    }
    if (gj == 0) {
        float* ksb = kvp + (size_t)c * CSTRIDE + KV_ELEMS + (size_t)g * TWO_D;
        ksb[i0] = sk[0];
        ksb[i0 + 1] = sk[1];
        ksb[64 + i0] = ck[0];
        ksb[64 + i0 + 1] = ck[1];
    }
}

// ---------------------------------------------------------------------------
// attn: head-major Q in; reduces kvp chunks inline; bf16 hi/lo (L,N,E) out.
// ---------------------------------------------------------------------------
__global__ __launch_bounds__(256) void attn_kernel(const float* __restrict__ Qh,
                                                   const float* __restrict__ kvp,
                                                   ushort* __restrict__ attnHi,
                                                   ushort* __restrict__ attnLo) {
    const int g = blockIdx.x;
    const int lt = blockIdx.y;
    const int nb = g >> 4, hh = g & 15;
    const int t = threadIdx.x;

    __shared__ float kvs[TWO_D][64];
    __shared__ float qT[TWO_D][64];
    __shared__ float sTab[64], cTab[64], ksS[TWO_D], pz[64][4], zs[64];

    {
        const float4* kv4 = (const float4*)(kvp + (size_t)g * TWO_D * D_DIM);
        const size_t cs4 = CSTRIDE / 4;
        float4* kvs4 = (float4*)&kvs[0][0];
        for (int s = t; s < TWO_D * D_DIM / 4; s += 256) {
            float4 a = kv4[s], b = kv4[s + cs4], c = kv4[s + 2 * cs4], d = kv4[s + 3 * cs4];
            kvs4[s] = make_float4(a.x + b.x + c.x + d.x, a.y + b.y + c.y + d.y,
                                  a.z + b.z + c.z + d.z, a.w + b.w + c.w + d.w);
        }
    }
    if (t < TWO_D) {
        const size_t o = KV_ELEMS + (size_t)g * TWO_D + t;
        ksS[t] = kvp[o] + kvp[o + CSTRIDE] + kvp[o + 2 * (size_t)CSTRIDE] + kvp[o + 3 * (size_t)CSTRIDE];
    }

    const int lbase = lt * 64;
    if (t < 64) {
        const float ang = 1.57079632679489662f * (float)(lbase + t + 1) / (float)L_DIM;
        sTab[t] = sinf(ang);
        cTab[t] = cosf(ang);
    }

    const int lq = t >> 2;
    const int dq = (t & 3) * 16;
    float qv[16];
    {
        const float* qrow = Qh + ((size_t)g * L_DIM + lbase + lq) * D_DIM + dq;
        *(float4*)&qv[0] = *(const float4*)&qrow[0];
        *(float4*)&qv[4] = *(const float4*)&qrow[4];
        *(float4*)&qv[8] = *(const float4*)&qrow[8];
        *(float4*)&qv[12] = *(const float4*)&qrow[12];
    }
    __syncthreads();

    {
        const float sl = sTab[lq], cl = cTab[lq];
#pragma unroll
        for (int jj = 0; jj < 16; ++jj) {
            qT[dq + jj][lq] = qv[jj] * sl;
            qT[64 + dq + jj][lq] = qv[jj] * cl;
        }
    }
    __syncthreads();

    {
        const int lz = t >> 2, qz = t & 3;
        float p = 0.f;
#pragma unroll
        for (int i = 0; i < 32; ++i) p = fmaf(qT[qz * 32 + i][lz], ksS[qz * 32 + i], p);
        pz[lz][qz] = p;
    }
    __syncthreads();
    if (t < 64) {
        const float s = pz[t][0] + pz[t][1] + pz[t][2] + pz[t][3];
        zs[t] = 1.0f / fmaxf(s, 1e-6f);
    }
    __syncthreads();

    const int ml = (t >> 4) * 4;
    const int nd = (t & 15) * 4;
    float acc[4][4];
#pragma unroll
    for (int i = 0; i < 4; ++i)
#pragma unroll
        for (int jj = 0; jj < 4; ++jj) acc[i][jj] = 0.f;

    for (int i = 0; i < TWO_D; ++i) {
        float4 a = *(float4*)&qT[i][ml];
        float4 b = *(float4*)&kvs[i][nd];
        acc[0][0] = fmaf(a.x, b.x, acc[0][0]); acc[0][1] = fmaf(a.x, b.y, acc[0][1]);
        acc[0][2] = fmaf(a.x, b.z, acc[0][2]); acc[0][3] = fmaf(a.x, b.w, acc[0][3]);
        acc[1][0] = fmaf(a.y, b.x, acc[1][0]); acc[1][1] = fmaf(a.y, b.y, acc[1][1]);
        acc[1][2] = fmaf(a.y, b.z, acc[1][2]); acc[1][3] = fmaf(a.y, b.w, acc[1][3]);
        acc[2][0] = fmaf(a.z, b.x, acc[2][0]); acc[2][1] = fmaf(a.z, b.y, acc[2][1]);
        acc[2][2] = fmaf(a.z, b.z, acc[2][2]); acc[2][3] = fmaf(a.z, b.w, acc[2][3]);
        acc[3][0] = fmaf(a.w, b.x, acc[3][0]); acc[3][1] = fmaf(a.w, b.y, acc[3][1]);
        acc[3][2] = fmaf(a.w, b.z, acc[3][2]); acc[3][3] = fmaf(a.w, b.w, acc[3][3]);
    }

#pragma unroll
    for (int r = 0; r < 4; ++r) {
        const float z = zs[ml + r];
        const float o0 = acc[r][0] * z, o1 = acc[r][1] * z;
        const float o2 = acc[r][2] * z, o3 = acc[r][3] * z;
        ushort4 hv, lv;
        hv.x = f2bf(o0); lv.x = f2bf(o0 - bf2f(hv.x));
        hv.y = f2bf(o1); lv.y = f2bf(o1 - bf2f(hv.y));
        hv.z = f2bf(o2); lv.z = f2bf(o2 - bf2f(hv.z));
        hv.w = f2bf(o3); lv.w = f2bf(o3 - bf2f(hv.w));
        const size_t base = (size_t)((lbase + ml + r) * N_DIM + nb) * E_DIM + hh * 64 + nd;
        *(ushort4*)&attnHi[base] = hv;
        *(ushort4*)&attnLo[base] = lv;
    }
}

// ---------------------------------------------------------------------------
extern "C" void kernel_launch(void* const* d_in, const int* in_sizes, int n_in,
                              void* d_out, int out_size, void* d_ws, size_t ws_size,
                              hipStream_t stream) {
    const float* X = (const float*)d_in[0];
    const float* Wq = (const float*)d_in[1];
    const float* Wk = (const float*)d_in[2];
    const float* Wv = (const float*)d_in[3];
    const float* Wo = (const float*)d_in[4];
    float* out = (float*)d_out;

    char* ws = (char*)d_ws;
    ushort* Xhi = (ushort*)(ws + 0);            // 32 MiB (later attnHi)
    ushort* Xlo = (ushort*)(ws + 33554432);     // 32 MiB (later attnLo)
    ushort* Whi = (ushort*)(ws + 67108864);     // 4 x 2 MiB (q,k,v,o)
    ushort* Wlo = (ushort*)(ws + 75497472);     // 4 x 2 MiB
    float* kvp  = (float*)(ws + 83886080);      // CH x 4.06 MiB
    float* bufA = (float*)(ws + 100925440);     // 64 MiB (Vh)
    // peak 160.25 MiB (proven plan)

    float* Kh = out;   // d_out doubles as scratch (Kh, then Qh, then output)
    float* Vh = bufA;
    float* Qh = out;

    const size_t WMAT = (size_t)E_DIM * E_DIM;

    split_fp32<<<2048, 256, 0, stream>>>(X, Xhi, Xlo, M_DIM * E_DIM / 4);
    split_w4<<<dim3(64, 4), 256, 0, stream>>>(Wq, Wk, Wv, Wo, Whi, Wlo);

    // fused K|V projection: B = [Wk; Wv] (2048 rows) -> Kh(relu), Vh
    // grid = 64 M-tiles x 8 N-tiles = 512
    gemm2<2, 8><<<512, 512, 0, stream>>>(Xhi, Xlo, Whi + 1 * WMAT, Wlo + 1 * WMAT, Kh, Vh);

    // kv partials (reduced inside attn)
    kv_partial<<<dim3(NHEADS, CH), 256, 0, stream>>>(Kh, Vh, kvp);

    // Q projection (Kh dead -> reuse d_out); grid = 64 x 4 = 256
    gemm2<1, 4><<<256, 512, 0, stream>>>(Xhi, Xlo, Whi + 0 * WMAT, Wlo + 0 * WMAT, Qh, nullptr);

    // attn -> bf16 hi/lo into X region (X dead)
    attn_kernel<<<dim3(NHEADS, L_DIM / 64), 256, 0, stream>>>(Qh, kvp, Xhi, Xlo);

    // out = attn Wo^T; grid = 64 x 4 = 256
    gemm2<0, 4><<<256, 512, 0, stream>>>(Xhi, Xlo, Whi + 3 * WMAT, Wlo + 3 * WMAT, out, nullptr);
}

// Round 10
// 467.511 us; speedup vs baseline: 1.4482x; 1.4482x over previous
//
#include <hip/hip_runtime.h>
#include <math.h>

#define L_DIM 2048
#define N_DIM 8
#define E_DIM 1024
#define H_DIM 16
#define D_DIM 64
#define M_DIM (L_DIM * N_DIM)     // 16384
#define NHEADS (N_DIM * H_DIM)    // 128
#define TWO_D 128
#define K_DIM 1024
#define CH 4                      // L-chunks for kv partials
#define LCH (L_DIM / CH)          // 512

#define KV_ELEMS (NHEADS * TWO_D * D_DIM)   // 1048576
#define KS_ELEMS (NHEADS * TWO_D)           // 16384
#define CSTRIDE (KV_ELEMS + KS_ELEMS)       // 1064960 floats per chunk

typedef __attribute__((ext_vector_type(8))) __bf16 bf16x8;
typedef __attribute__((ext_vector_type(4))) float f32x4;
typedef __attribute__((ext_vector_type(8))) ushort u16x8;

__device__ __forceinline__ ushort f2bf(float x) {
    union { float f; unsigned u; } a; a.f = x;
    unsigned r = a.u + 0x7fffu + ((a.u >> 16) & 1u);
    return (ushort)(r >> 16);
}
__device__ __forceinline__ float bf2f(ushort h) {
    union { unsigned u; float f; } a; a.u = ((unsigned)h) << 16;
    return a.f;
}

__device__ __forceinline__ void gload_lds16(const void* g, void* l) {
    __builtin_amdgcn_global_load_lds((const __attribute__((address_space(1))) void*)g,
                                     (__attribute__((address_space(3))) void*)l, 16, 0, 0);
}

// ---------------------------------------------------------------------------
// split fp32 -> bf16 hi + lo
// ---------------------------------------------------------------------------
__global__ __launch_bounds__(256) void split_fp32(const float* __restrict__ in,
                                                  ushort* __restrict__ hi,
                                                  ushort* __restrict__ lo, int n4) {
    int i = blockIdx.x * 256 + threadIdx.x;
    const int stride = gridDim.x * 256;
    for (; i < n4; i += stride) {
        float4 v = ((const float4*)in)[i];
        ushort h0 = f2bf(v.x), h1 = f2bf(v.y), h2 = f2bf(v.z), h3 = f2bf(v.w);
        ushort l0 = f2bf(v.x - bf2f(h0)), l1 = f2bf(v.y - bf2f(h1));
        ushort l2 = f2bf(v.z - bf2f(h2)), l3 = f2bf(v.w - bf2f(h3));
        ((ushort4*)hi)[i] = make_ushort4(h0, h1, h2, h3);
        ((ushort4*)lo)[i] = make_ushort4(l0, l1, l2, l3);
    }
}

__global__ __launch_bounds__(256) void split_w4(const float* __restrict__ w0,
                                                const float* __restrict__ w1,
                                                const float* __restrict__ w2,
                                                const float* __restrict__ w3,
                                                ushort* __restrict__ hi,
                                                ushort* __restrict__ lo) {
    const int midx = blockIdx.y;
    const float* src = (midx == 0) ? w0 : (midx == 1) ? w1 : (midx == 2) ? w2 : w3;
    hi += (size_t)midx * E_DIM * E_DIM;
    lo += (size_t)midx * E_DIM * E_DIM;
    const int n4 = E_DIM * E_DIM / 4;
    int i = blockIdx.x * 256 + threadIdx.x;
    const int stride = gridDim.x * 256;
    for (; i < n4; i += stride) {
        float4 v = ((const float4*)src)[i];
        ushort h0 = f2bf(v.x), h1 = f2bf(v.y), h2 = f2bf(v.z), h3 = f2bf(v.w);
        ushort l0 = f2bf(v.x - bf2f(h0)), l1 = f2bf(v.y - bf2f(h1));
        ushort l2 = f2bf(v.z - bf2f(h2)), l3 = f2bf(v.w - bf2f(h3));
        ((ushort4*)hi)[i] = make_ushort4(h0, h1, h2, h3);
        ((ushort4*)lo)[i] = make_ushort4(l0, l1, l2, l3);
    }
}

// ---------------------------------------------------------------------------
// split-bf16 MFMA GEMM-NT, 256x256 tile, BK=32, 8 waves (2M x 4N, 128x64/wave).
// EXACT round-7 kernel (538 us verified): dbuf LDS via global_load_lds,
// STAGE(next) -> compute(cur) -> __syncthreads, conflict-free XOR swizzle.
// OUTMODE 0: row-major fp32; 1: head-major+relu (Q); 2: fused K|V head-major.
// ---------------------------------------------------------------------------
template <int OUTMODE, int NBS>
__global__ __launch_bounds__(512, 2) void gemm2(const ushort* __restrict__ Ahi,
                                                const ushort* __restrict__ Alo,
                                                const ushort* __restrict__ Bhi,
                                                const ushort* __restrict__ Blo,
                                                float* __restrict__ C,
                                                float* __restrict__ C2) {
    // buffer (ushorts): Ah[0,8192) Al[8192,16384) Bh[16384,24576) Bl[24576,32768)
    __shared__ ushort smem[2][32768];  // 128 KiB

    const int t = threadIdx.x;
    const int wid = t >> 6;
    const int lane = t & 63;

    const int x = blockIdx.x;
    const int cxcd = x & 7;
    const int j = x >> 3;                 // 0 .. 8*NBS-1
    const int mb = cxcd * 8 + j / NBS;    // 0..63
    const int nb = j % NBS;
    const int m0 = mb * 256, n0 = nb * 256;

    const int srow = t >> 2;                  // 0..127
    const int sch = t & 3;
    const int gch = sch ^ ((srow >> 1) & 3);  // invariant under row+128
    const size_t aOff = (size_t)(m0 + srow) * K_DIM + gch * 8;
    const size_t bOff = (size_t)(n0 + srow) * K_DIM + gch * 8;
    const size_t H128 = (size_t)128 * K_DIM;

#define STAGE(b, kt1)                                             \
    do {                                                          \
        const size_t kc_ = (size_t)(kt1) * 32;                    \
        ushort* d = (ushort*)&smem[b][0] + wid * 512;             \
        gload_lds16(Ahi + aOff + kc_, d);                         \
        gload_lds16(Ahi + aOff + H128 + kc_, d + 4096);           \
        gload_lds16(Alo + aOff + kc_, d + 8192);                  \
        gload_lds16(Alo + aOff + H128 + kc_, d + 12288);          \
        gload_lds16(Bhi + bOff + kc_, d + 16384);                 \
        gload_lds16(Bhi + bOff + H128 + kc_, d + 20480);          \
        gload_lds16(Blo + bOff + kc_, d + 24576);                 \
        gload_lds16(Blo + bOff + H128 + kc_, d + 28672);          \
    } while (0)

    const int wm = wid >> 2;       // 0..1 -> M half (stride 128)
    const int wn = wid & 3;        // 0..3 -> N quarter (stride 64)
    const int lr = lane & 15;
    const int kc = lane >> 4;
    int aoff[8], boff[4];
#pragma unroll
    for (int m = 0; m < 8; ++m) {
        const int r = wm * 128 + m * 16 + lr;
        aoff[m] = r * 32 + ((kc ^ ((r >> 1) & 3)) << 3);
    }
#pragma unroll
    for (int n = 0; n < 4; ++n) {
        const int r = wn * 64 + n * 16 + lr;
        boff[n] = r * 32 + ((kc ^ ((r >> 1) & 3)) << 3);
    }

    f32x4 acc[8][4];
    const f32x4 zv = {0.f, 0.f, 0.f, 0.f};
#pragma unroll
    for (int m = 0; m < 8; ++m)
#pragma unroll
        for (int n = 0; n < 4; ++n) acc[m][n] = zv;

    const int NK = K_DIM / 32;  // 32

    STAGE(0, 0);
    __syncthreads();

#pragma unroll 1
    for (int kt = 0; kt < NK; ++kt) {
        const int cb = kt & 1;
        if (kt + 1 < NK) STAGE(cb ^ 1, kt + 1);

        const ushort* bb = smem[cb];
        bf16x8 bh[4], bl[4];
#pragma unroll
        for (int n = 0; n < 4; ++n) {
            bh[n] = *(const bf16x8*)&bb[16384 + boff[n]];
            bl[n] = *(const bf16x8*)&bb[24576 + boff[n]];
        }
#pragma unroll
        for (int m = 0; m < 8; ++m) {
            const bf16x8 ah = *(const bf16x8*)&bb[aoff[m]];
            const bf16x8 al = *(const bf16x8*)&bb[8192 + aoff[m]];
#pragma unroll
            for (int n = 0; n < 4; ++n) {
                acc[m][n] = __builtin_amdgcn_mfma_f32_16x16x32_bf16(ah, bh[n], acc[m][n], 0, 0, 0);
                acc[m][n] = __builtin_amdgcn_mfma_f32_16x16x32_bf16(ah, bl[n], acc[m][n], 0, 0, 0);
                acc[m][n] = __builtin_amdgcn_mfma_f32_16x16x32_bf16(al, bh[n], acc[m][n], 0, 0, 0);
            }
        }
        __syncthreads();
    }

    const int erow = (lane >> 4) * 4;
    const int ecol = lane & 15;
#pragma unroll
    for (int m = 0; m < 8; ++m) {
        const int grb = m0 + wm * 128 + m * 16 + erow;
#pragma unroll
        for (int n = 0; n < 4; ++n) {
            const int gc = n0 + wn * 64 + n * 16 + ecol;
            f32x4 v = acc[m][n];
#pragma unroll
            for (int q = 0; q < 4; ++q) {
                const int gr = grb + q;
                float val = v[q];
                if constexpr (OUTMODE == 0) {
                    C[(size_t)gr * E_DIM + gc] = val;
                } else if constexpr (OUTMODE == 1) {
                    val = fmaxf(val, 0.f);
                    const int hh = gc >> 6, d = gc & 63;
                    C[((size_t)((gr & 7) * 16 + hh) * L_DIM + (gr >> 3)) * D_DIM + d] = val;
                } else {
                    const int mat = gc >> 10;  // 0 = K (relu), 1 = V
                    const int col = gc & 1023;
                    if (mat == 0) val = fmaxf(val, 0.f);
                    const int hh = col >> 6, d = col & 63;
                    float* dstc = mat ? C2 : C;
                    dstc[((size_t)((gr & 7) * 16 + hh) * L_DIM + (gr >> 3)) * D_DIM + d] = val;
                }
            }
        }
    }
#undef STAGE
}

// ---------------------------------------------------------------------------
// kv partials from head-major K/V (contiguous streams, no atomics) — r7 exact.
// ---------------------------------------------------------------------------
__global__ __launch_bounds__(256) void kv_partial(const float* __restrict__ Kh,
                                                  const float* __restrict__ Vh,
                                                  float* __restrict__ kvp) {
    const int g = blockIdx.x;
    const int c = blockIdx.y;
    const int t = threadIdx.x;

    __shared__ float Kt[32][64];
    __shared__ float Vt[32][64];
    __shared__ float sT[32], cT[32];

    const int gi = t >> 3;
    const int gj = t & 7;
    const int i0 = gi * 2, j0 = gj * 8;

    float S[2][8], Cc[2][8];
#pragma unroll
    for (int i = 0; i < 2; ++i)
#pragma unroll
        for (int jj = 0; jj < 8; ++jj) { S[i][jj] = 0.f; Cc[i][jj] = 0.f; }
    float sk[2] = {0.f, 0.f}, ck[2] = {0.f, 0.f};

    for (int lt = 0; lt < LCH; lt += 32) {
        const int lbase = c * LCH + lt;
        const float4* ks = (const float4*)&Kh[((size_t)g * L_DIM + lbase) * D_DIM];
        const float4* vs = (const float4*)&Vh[((size_t)g * L_DIM + lbase) * D_DIM];
        ((float4*)&Kt[0][0])[t] = ks[t];
        ((float4*)&Kt[0][0])[t + 256] = ks[t + 256];
        ((float4*)&Vt[0][0])[t] = vs[t];
        ((float4*)&Vt[0][0])[t + 256] = vs[t + 256];
        if (t < 32) {
            const float ang = 1.57079632679489662f * (float)(lbase + t + 1) / (float)L_DIM;
            sT[t] = sinf(ang);
            cT[t] = cosf(ang);
        }
        __syncthreads();
#pragma unroll 4
        for (int lr = 0; lr < 32; ++lr) {
            const float sl = sT[lr], cl = cT[lr];
            const float k0v = Kt[lr][i0], k1v = Kt[lr][i0 + 1];
            const float ks0 = k0v * sl, ks1 = k1v * sl;
            const float kc0 = k0v * cl, kc1 = k1v * cl;
            sk[0] += ks0; sk[1] += ks1; ck[0] += kc0; ck[1] += kc1;
            float v8[8];
            *(float4*)&v8[0] = *(float4*)&Vt[lr][j0];
            *(float4*)&v8[4] = *(float4*)&Vt[lr][j0 + 4];
#pragma unroll
            for (int jj = 0; jj < 8; ++jj) {
                S[0][jj] = fmaf(ks0, v8[jj], S[0][jj]);
                S[1][jj] = fmaf(ks1, v8[jj], S[1][jj]);
                Cc[0][jj] = fmaf(kc0, v8[jj], Cc[0][jj]);
                Cc[1][jj] = fmaf(kc1, v8[jj], Cc[1][jj]);
            }
        }
        __syncthreads();
    }

    float* kvb = kvp + (size_t)c * CSTRIDE + (size_t)g * TWO_D * D_DIM;
#pragma unroll
    for (int ii = 0; ii < 2; ++ii) {
        *(float4*)&kvb[(size_t)(i0 + ii) * D_DIM + j0] =
            make_float4(S[ii][0], S[ii][1], S[ii][2], S[ii][3]);
        *(float4*)&kvb[(size_t)(i0 + ii) * D_DIM + j0 + 4] =
            make_float4(S[ii][4], S[ii][5], S[ii][6], S[ii][7]);
        *(float4*)&kvb[(size_t)(64 + i0 + ii) * D_DIM + j0] =
            make_float4(Cc[ii][0], Cc[ii][1], Cc[ii][2], Cc[ii][3]);
        *(float4*)&kvb[(size_t)(64 + i0 + ii) * D_DIM + j0 + 4] =
            make_float4(Cc[ii][4], Cc[ii][5], Cc[ii][6], Cc[ii][7]);
    }
    if (gj == 0) {
        float* ksb = kvp + (size_t)c * CSTRIDE + KV_ELEMS + (size_t)g * TWO_D;
        ksb[i0] = sk[0];
        ksb[i0 + 1] = sk[1];
        ksb[64 + i0] = ck[0];
        ksb[64 + i0 + 1] = ck[1];
    }
}

// ---------------------------------------------------------------------------
// attn via MFMA: per (head g, group of 4 l-tiles). kv^T staged once as bf16
// hi/lo (XOR-swizzled, ds_write+ds_read both swizzled); per tile: q -> q_
// hi/lo in LDS, z from registers, 16x16x32 split-bf16 MFMA, scaled bf16
// hi/lo output in (L,N,E).
// ---------------------------------------------------------------------------
__global__ __launch_bounds__(256) void attn_mfma(const float* __restrict__ Qh,
                                                 const float* __restrict__ kvp,
                                                 ushort* __restrict__ attnHi,
                                                 ushort* __restrict__ attnLo) {
    const int g = blockIdx.x;
    const int ltg = blockIdx.y;          // 0..7 (4 l-tiles of 64 each)
    const int nb = g >> 4, hh = g & 15;
    const int t = threadIdx.x;
    const int wid = t >> 6, lane = t & 63;

    __shared__ ushort kvbH[4][64][32];   // [ks][d][k'] 16 KiB
    __shared__ ushort kvbL[4][64][32];
    __shared__ ushort qaH[4][64][32];    // [ks][l][k']
    __shared__ ushort qaL[4][64][32];
    __shared__ float ksS[TWO_D];
    __shared__ float pz[64][4];
    __shared__ float zs[64];

    // ---- ksum (4-chunk reduce) ----
    if (t < TWO_D) {
        const size_t o = KV_ELEMS + (size_t)g * TWO_D + t;
        ksS[t] = kvp[o] + kvp[o + CSTRIDE] + kvp[o + 2 * (size_t)CSTRIDE] +
                 kvp[o + 3 * (size_t)CSTRIDE];
    }

    // ---- kv^T staging: kvp [128 i][64 d] fp32 -> kvb[ks][d][k'] bf16 hi/lo
    {
        const float* kvg = kvp + (size_t)g * TWO_D * D_DIM;
        const int d = t & 63;
        const int igb = t >> 6;          // 0..3
        const int csd = (d >> 1) & 3;
#pragma unroll
        for (int rep = 0; rep < 4; ++rep) {
            const int i0 = (rep * 4 + igb) * 8;   // 0,8,...,120
            float v[8];
#pragma unroll
            for (int jj = 0; jj < 8; ++jj) {
                const size_t o = (size_t)(i0 + jj) * D_DIM + d;
                v[jj] = kvg[o] + kvg[o + CSTRIDE] + kvg[o + 2 * (size_t)CSTRIDE] +
                        kvg[o + 3 * (size_t)CSTRIDE];
            }
            const int ks = i0 >> 5;
            const int cs = ((((i0 >> 3) & 3) ^ csd) << 3);
            u16x8 h, l;
#pragma unroll
            for (int jj = 0; jj < 8; ++jj) {
                h[jj] = f2bf(v[jj]);
                l[jj] = f2bf(v[jj] - bf2f(h[jj]));
            }
            *(u16x8*)&kvbH[ks][d][cs] = h;
            *(u16x8*)&kvbL[ks][d][cs] = l;
        }
    }

    const int lq = t >> 2;               // 0..63 (q row)
    const int dq = (t & 3) * 16;         // d sub-block
    const int csq = (lq >> 1) & 3;

    // fragment constants (identical mapping to gemm2)
    const int lr = lane & 15, kc = lane >> 4;
    const int arow = wid * 16 + lr;
    const int aco = ((kc ^ ((arow >> 1) & 3)) << 3);
    int bro[4], bco[4];
#pragma unroll
    for (int n = 0; n < 4; ++n) {
        bro[n] = n * 16 + lr;
        bco[n] = ((kc ^ ((bro[n] >> 1) & 3)) << 3);
    }
    const int erow = (lane >> 4) * 4;
    const int ecol = lane & 15;

    __syncthreads();   // kvb + ksS ready

#pragma unroll 1
    for (int it = 0; it < 4; ++it) {
        const int lbase = (ltg * 4 + it) * 64;

        // load q row (fp32, head-major)
        float qv[16];
        const float* qrow = Qh + ((size_t)g * L_DIM + lbase + lq) * D_DIM + dq;
        *(float4*)&qv[0] = *(const float4*)&qrow[0];
        *(float4*)&qv[4] = *(const float4*)&qrow[4];
        *(float4*)&qv[8] = *(const float4*)&qrow[8];
        *(float4*)&qv[12] = *(const float4*)&qrow[12];
        const float ang = 1.57079632679489662f * (float)(lbase + lq + 1) / (float)L_DIM;
        const float sl = sinf(ang), cl = cosf(ang);

        // z partial straight from registers
        float p = 0.f;
#pragma unroll
        for (int jj = 0; jj < 16; ++jj)
            p += qv[jj] * (sl * ksS[dq + jj] + cl * ksS[64 + dq + jj]);
        pz[lq][t & 3] = p;

        // q_ hi/lo into qa (sin part i=dq+j, cos part i=64+dq+j)
#pragma unroll
        for (int jg = 0; jg < 2; ++jg) {
            const int ib = dq + jg * 8;
            const int ks = ib >> 5;
            const int cs = ((((ib >> 3) & 3) ^ csq) << 3);
            u16x8 hs, ls, hc, lc;
#pragma unroll
            for (int jj = 0; jj < 8; ++jj) {
                const float vs = qv[jg * 8 + jj] * sl;
                const float vc = qv[jg * 8 + jj] * cl;
                hs[jj] = f2bf(vs); ls[jj] = f2bf(vs - bf2f(hs[jj]));
                hc[jj] = f2bf(vc); lc[jj] = f2bf(vc - bf2f(hc[jj]));
            }
            *(u16x8*)&qaH[ks][lq][cs] = hs;
            *(u16x8*)&qaL[ks][lq][cs] = ls;
            *(u16x8*)&qaH[ks + 2][lq][cs] = hc;
            *(u16x8*)&qaL[ks + 2][lq][cs] = lc;
        }
        __syncthreads();
        if (t < 64) {
            const float s = pz[t][0] + pz[t][1] + pz[t][2] + pz[t][3];
            zs[t] = 1.0f / fmaxf(s, 1e-6f);
        }
        __syncthreads();

        // MFMA: out(64x64) = q_(64x128) * kv(128x64), K-steps of 32
        f32x4 acc[4];
        const f32x4 zv = {0.f, 0.f, 0.f, 0.f};
#pragma unroll
        for (int n = 0; n < 4; ++n) acc[n] = zv;
#pragma unroll
        for (int ks = 0; ks < 4; ++ks) {
            const bf16x8 ah = *(const bf16x8*)&qaH[ks][arow][aco];
            const bf16x8 al = *(const bf16x8*)&qaL[ks][arow][aco];
#pragma unroll
            for (int n = 0; n < 4; ++n) {
                const bf16x8 bh = *(const bf16x8*)&kvbH[ks][bro[n]][bco[n]];
                const bf16x8 bl = *(const bf16x8*)&kvbL[ks][bro[n]][bco[n]];
                acc[n] = __builtin_amdgcn_mfma_f32_16x16x32_bf16(ah, bh, acc[n], 0, 0, 0);
                acc[n] = __builtin_amdgcn_mfma_f32_16x16x32_bf16(ah, bl, acc[n], 0, 0, 0);
                acc[n] = __builtin_amdgcn_mfma_f32_16x16x32_bf16(al, bh, acc[n], 0, 0, 0);
            }
        }

        // epilogue: scale by z, hi/lo convert, store (L,N,E)
#pragma unroll
        for (int n = 0; n < 4; ++n) {
#pragma unroll
            for (int q = 0; q < 4; ++q) {
                const int lrow = wid * 16 + erow + q;
                const float val = acc[n][q] * zs[lrow];
                const int d = n * 16 + ecol;
                const ushort hv = f2bf(val);
                const ushort lv = f2bf(val - bf2f(hv));
                const size_t base = (size_t)((lbase + lrow) * N_DIM + nb) * E_DIM + hh * 64 + d;
                attnHi[base] = hv;
                attnLo[base] = lv;
            }
        }
        __syncthreads();   // before next tile overwrites qa
    }
}

// ---------------------------------------------------------------------------
extern "C" void kernel_launch(void* const* d_in, const int* in_sizes, int n_in,
                              void* d_out, int out_size, void* d_ws, size_t ws_size,
                              hipStream_t stream) {
    const float* X = (const float*)d_in[0];
    const float* Wq = (const float*)d_in[1];
    const float* Wk = (const float*)d_in[2];
    const float* Wv = (const float*)d_in[3];
    const float* Wo = (const float*)d_in[4];
    float* out = (float*)d_out;

    char* ws = (char*)d_ws;
    ushort* Xhi = (ushort*)(ws + 0);            // 32 MiB (later attnHi)
    ushort* Xlo = (ushort*)(ws + 33554432);     // 32 MiB (later attnLo)
    ushort* Whi = (ushort*)(ws + 67108864);     // 4 x 2 MiB (q,k,v,o)
    ushort* Wlo = (ushort*)(ws + 75497472);     // 4 x 2 MiB
    float* kvp  = (float*)(ws + 83886080);      // CH x 4.06 MiB
    float* bufA = (float*)(ws + 100925440);     // 64 MiB (Vh)
    // peak 160.25 MiB (proven plan)

    float* Kh = out;   // d_out doubles as scratch (Kh, then Qh, then output)
    float* Vh = bufA;
    float* Qh = out;

    const size_t WMAT = (size_t)E_DIM * E_DIM;

    split_fp32<<<2048, 256, 0, stream>>>(X, Xhi, Xlo, M_DIM * E_DIM / 4);
    split_w4<<<dim3(64, 4), 256, 0, stream>>>(Wq, Wk, Wv, Wo, Whi, Wlo);

    // fused K|V projection: B = [Wk; Wv] (2048 rows) -> Kh(relu), Vh
    gemm2<2, 8><<<512, 512, 0, stream>>>(Xhi, Xlo, Whi + 1 * WMAT, Wlo + 1 * WMAT, Kh, Vh);

    // kv partials (reduced inside attn)
    kv_partial<<<dim3(NHEADS, CH), 256, 0, stream>>>(Kh, Vh, kvp);

    // Q projection (Kh dead -> reuse d_out); grid = 64 x 4 = 256
    gemm2<1, 4><<<256, 512, 0, stream>>>(Xhi, Xlo, Whi + 0 * WMAT, Wlo + 0 * WMAT, Qh, nullptr);

    // attn (MFMA) -> bf16 hi/lo into X region (X dead)
    attn_mfma<<<dim3(NHEADS, L_DIM / 256), 256, 0, stream>>>(Qh, kvp, Xhi, Xlo);

    // out = attn Wo^T; grid = 64 x 4 = 256
    gemm2<0, 4><<<256, 512, 0, stream>>>(Xhi, Xlo, Whi + 3 * WMAT, Wlo + 3 * WMAT, out, nullptr);
}

// Round 11
// 462.174 us; speedup vs baseline: 1.4649x; 1.0115x over previous
//
#include <hip/hip_runtime.h>
#include <math.h>

#define L_DIM 2048
#define N_DIM 8
#define E_DIM 1024
#define H_DIM 16
#define D_DIM 64
#define M_DIM (L_DIM * N_DIM)     // 16384
#define NHEADS (N_DIM * H_DIM)    // 128
#define TWO_D 128
#define K_DIM 1024
#define CH 4                      // L-chunks for kv partials
#define LCH (L_DIM / CH)          // 512

#define KV_ELEMS (NHEADS * TWO_D * D_DIM)   // 1048576
#define KS_ELEMS (NHEADS * TWO_D)           // 16384
#define CSTRIDE (KV_ELEMS + KS_ELEMS)       // 1064960 floats per chunk

typedef __attribute__((ext_vector_type(8))) __bf16 bf16x8;
typedef __attribute__((ext_vector_type(4))) float f32x4;
typedef __attribute__((ext_vector_type(8))) ushort u16x8;

__device__ __forceinline__ ushort f2bf(float x) {
    union { float f; unsigned u; } a; a.f = x;
    unsigned r = a.u + 0x7fffu + ((a.u >> 16) & 1u);
    return (ushort)(r >> 16);
}
__device__ __forceinline__ float bf2f(ushort h) {
    union { unsigned u; float f; } a; a.u = ((unsigned)h) << 16;
    return a.f;
}

__device__ __forceinline__ void gload_lds16(const void* g, void* l) {
    __builtin_amdgcn_global_load_lds((const __attribute__((address_space(1))) void*)g,
                                     (__attribute__((address_space(3))) void*)l, 16, 0, 0);
}

// ---------------------------------------------------------------------------
// split fp32 -> bf16 hi + lo for X and all four W matrices, one launch.
// ---------------------------------------------------------------------------
__global__ __launch_bounds__(256) void split_all(const float* __restrict__ X,
                                                 const float* __restrict__ W0,
                                                 const float* __restrict__ W1,
                                                 const float* __restrict__ W2,
                                                 const float* __restrict__ W3,
                                                 ushort* __restrict__ Xhi,
                                                 ushort* __restrict__ Xlo,
                                                 ushort* __restrict__ Whi,
                                                 ushort* __restrict__ Wlo) {
    const int NX4 = M_DIM * E_DIM / 4;   // 4194304
    const int NW4 = E_DIM * E_DIM / 4;   // 262144 = 2^18
    const int total = NX4 + 4 * NW4;
    int i = blockIdx.x * 256 + threadIdx.x;
    const int stride = gridDim.x * 256;
    for (; i < total; i += stride) {
        const float4* src;
        ushort4 *dhi, *dlo;
        int idx;
        if (i < NX4) {
            src = (const float4*)X;
            dhi = (ushort4*)Xhi;
            dlo = (ushort4*)Xlo;
            idx = i;
        } else {
            const int r = i - NX4;
            const int w = r >> 18;
            idx = r & (NW4 - 1);
            const float* ws_ = (w == 0) ? W0 : (w == 1) ? W1 : (w == 2) ? W2 : W3;
            src = (const float4*)ws_;
            dhi = (ushort4*)(Whi + (size_t)w * E_DIM * E_DIM);
            dlo = (ushort4*)(Wlo + (size_t)w * E_DIM * E_DIM);
        }
        float4 v = src[idx];
        ushort h0 = f2bf(v.x), h1 = f2bf(v.y), h2 = f2bf(v.z), h3 = f2bf(v.w);
        ushort l0 = f2bf(v.x - bf2f(h0)), l1 = f2bf(v.y - bf2f(h1));
        ushort l2 = f2bf(v.z - bf2f(h2)), l3 = f2bf(v.w - bf2f(h3));
        dhi[idx] = make_ushort4(h0, h1, h2, h3);
        dlo[idx] = make_ushort4(l0, l1, l2, l3);
    }
}

// ---------------------------------------------------------------------------
// split-bf16 MFMA GEMM-NT, 256x256 tile, BK=32, 8 waves (2M x 4N, 128x64/wave).
// EXACT round-7/10 kernel (verified): dbuf LDS via global_load_lds,
// STAGE(next) -> compute(cur) -> __syncthreads, conflict-free XOR swizzle.
// OUTMODE 0: row-major fp32; 1: head-major+relu (Q); 2: fused K|V head-major.
// ---------------------------------------------------------------------------
template <int OUTMODE, int NBS>
__global__ __launch_bounds__(512, 2) void gemm2(const ushort* __restrict__ Ahi,
                                                const ushort* __restrict__ Alo,
                                                const ushort* __restrict__ Bhi,
                                                const ushort* __restrict__ Blo,
                                                float* __restrict__ C,
                                                float* __restrict__ C2) {
    // buffer (ushorts): Ah[0,8192) Al[8192,16384) Bh[16384,24576) Bl[24576,32768)
    __shared__ ushort smem[2][32768];  // 128 KiB

    const int t = threadIdx.x;
    const int wid = t >> 6;
    const int lane = t & 63;

    const int x = blockIdx.x;
    const int cxcd = x & 7;
    const int j = x >> 3;                 // 0 .. 8*NBS-1
    const int mb = cxcd * 8 + j / NBS;    // 0..63
    const int nb = j % NBS;
    const int m0 = mb * 256, n0 = nb * 256;

    const int srow = t >> 2;                  // 0..127
    const int sch = t & 3;
    const int gch = sch ^ ((srow >> 1) & 3);  // invariant under row+128
    const size_t aOff = (size_t)(m0 + srow) * K_DIM + gch * 8;
    const size_t bOff = (size_t)(n0 + srow) * K_DIM + gch * 8;
    const size_t H128 = (size_t)128 * K_DIM;

#define STAGE(b, kt1)                                             \
    do {                                                          \
        const size_t kc_ = (size_t)(kt1) * 32;                    \
        ushort* d = (ushort*)&smem[b][0] + wid * 512;             \
        gload_lds16(Ahi + aOff + kc_, d);                         \
        gload_lds16(Ahi + aOff + H128 + kc_, d + 4096);           \
        gload_lds16(Alo + aOff + kc_, d + 8192);                  \
        gload_lds16(Alo + aOff + H128 + kc_, d + 12288);          \
        gload_lds16(Bhi + bOff + kc_, d + 16384);                 \
        gload_lds16(Bhi + bOff + H128 + kc_, d + 20480);          \
        gload_lds16(Blo + bOff + kc_, d + 24576);                 \
        gload_lds16(Blo + bOff + H128 + kc_, d + 28672);          \
    } while (0)

    const int wm = wid >> 2;       // 0..1 -> M half (stride 128)
    const int wn = wid & 3;        // 0..3 -> N quarter (stride 64)
    const int lr = lane & 15;
    const int kc = lane >> 4;
    int aoff[8], boff[4];
#pragma unroll
    for (int m = 0; m < 8; ++m) {
        const int r = wm * 128 + m * 16 + lr;
        aoff[m] = r * 32 + ((kc ^ ((r >> 1) & 3)) << 3);
    }
#pragma unroll
    for (int n = 0; n < 4; ++n) {
        const int r = wn * 64 + n * 16 + lr;
        boff[n] = r * 32 + ((kc ^ ((r >> 1) & 3)) << 3);
    }

    f32x4 acc[8][4];
    const f32x4 zv = {0.f, 0.f, 0.f, 0.f};
#pragma unroll
    for (int m = 0; m < 8; ++m)
#pragma unroll
        for (int n = 0; n < 4; ++n) acc[m][n] = zv;

    const int NK = K_DIM / 32;  // 32

    STAGE(0, 0);
    __syncthreads();

#pragma unroll 1
    for (int kt = 0; kt < NK; ++kt) {
        const int cb = kt & 1;
        if (kt + 1 < NK) STAGE(cb ^ 1, kt + 1);

        const ushort* bb = smem[cb];
        bf16x8 bh[4], bl[4];
#pragma unroll
        for (int n = 0; n < 4; ++n) {
            bh[n] = *(const bf16x8*)&bb[16384 + boff[n]];
            bl[n] = *(const bf16x8*)&bb[24576 + boff[n]];
        }
#pragma unroll
        for (int m = 0; m < 8; ++m) {
            const bf16x8 ah = *(const bf16x8*)&bb[aoff[m]];
            const bf16x8 al = *(const bf16x8*)&bb[8192 + aoff[m]];
#pragma unroll
            for (int n = 0; n < 4; ++n) {
                acc[m][n] = __builtin_amdgcn_mfma_f32_16x16x32_bf16(ah, bh[n], acc[m][n], 0, 0, 0);
                acc[m][n] = __builtin_amdgcn_mfma_f32_16x16x32_bf16(ah, bl[n], acc[m][n], 0, 0, 0);
                acc[m][n] = __builtin_amdgcn_mfma_f32_16x16x32_bf16(al, bh[n], acc[m][n], 0, 0, 0);
            }
        }
        __syncthreads();
    }

    const int erow = (lane >> 4) * 4;
    const int ecol = lane & 15;
#pragma unroll
    for (int m = 0; m < 8; ++m) {
        const int grb = m0 + wm * 128 + m * 16 + erow;
#pragma unroll
        for (int n = 0; n < 4; ++n) {
            const int gc = n0 + wn * 64 + n * 16 + ecol;
            f32x4 v = acc[m][n];
#pragma unroll
            for (int q = 0; q < 4; ++q) {
                const int gr = grb + q;
                float val = v[q];
                if constexpr (OUTMODE == 0) {
                    C[(size_t)gr * E_DIM + gc] = val;
                } else if constexpr (OUTMODE == 1) {
                    val = fmaxf(val, 0.f);
                    const int hh = gc >> 6, d = gc & 63;
                    C[((size_t)((gr & 7) * 16 + hh) * L_DIM + (gr >> 3)) * D_DIM + d] = val;
                } else {
                    const int mat = gc >> 10;  // 0 = K (relu), 1 = V
                    const int col = gc & 1023;
                    if (mat == 0) val = fmaxf(val, 0.f);
                    const int hh = col >> 6, d = col & 63;
                    float* dstc = mat ? C2 : C;
                    dstc[((size_t)((gr & 7) * 16 + hh) * L_DIM + (gr >> 3)) * D_DIM + d] = val;
                }
            }
        }
    }
#undef STAGE
}

// ---------------------------------------------------------------------------
// kv partials from head-major K/V — now double-buffered (reg-stage next tile,
// single __syncthreads per iteration; write(it,b) ordered after
// compute(it-2,b) via sync(it-1)).
// ---------------------------------------------------------------------------
__global__ __launch_bounds__(256) void kv_partial(const float* __restrict__ Kh,
                                                  const float* __restrict__ Vh,
                                                  float* __restrict__ kvp) {
    const int g = blockIdx.x;
    const int c = blockIdx.y;
    const int t = threadIdx.x;

    __shared__ float Kt[2][32][64];
    __shared__ float Vt[2][32][64];
    __shared__ float sT[2][32], cT[2][32];

    const int gi = t >> 3;
    const int gj = t & 7;
    const int i0 = gi * 2, j0 = gj * 8;

    float S[2][8], Cc[2][8];
#pragma unroll
    for (int i = 0; i < 2; ++i)
#pragma unroll
        for (int jj = 0; jj < 8; ++jj) { S[i][jj] = 0.f; Cc[i][jj] = 0.f; }
    float sk[2] = {0.f, 0.f}, ck[2] = {0.f, 0.f};

    const int NIT = LCH / 32;  // 16
    float4 rk0, rk1, rv0, rv1;
    float rs = 0.f, rc_ = 0.f;

#define LOADT(it)                                                              \
    do {                                                                       \
        const int lbase_ = c * LCH + (it) * 32;                                \
        const float4* ks_ = (const float4*)&Kh[((size_t)g * L_DIM + lbase_) * D_DIM]; \
        const float4* vs_ = (const float4*)&Vh[((size_t)g * L_DIM + lbase_) * D_DIM]; \
        rk0 = ks_[t]; rk1 = ks_[t + 256];                                      \
        rv0 = vs_[t]; rv1 = vs_[t + 256];                                      \
        if (t < 32) {                                                          \
            const float ang_ = 1.57079632679489662f * (float)(lbase_ + t + 1) / (float)L_DIM; \
            rs = sinf(ang_); rc_ = cosf(ang_);                                 \
        }                                                                      \
    } while (0)

    LOADT(0);
#pragma unroll 1
    for (int it = 0; it < NIT; ++it) {
        const int b = it & 1;
        ((float4*)&Kt[b][0][0])[t] = rk0;
        ((float4*)&Kt[b][0][0])[t + 256] = rk1;
        ((float4*)&Vt[b][0][0])[t] = rv0;
        ((float4*)&Vt[b][0][0])[t + 256] = rv1;
        if (t < 32) { sT[b][t] = rs; cT[b][t] = rc_; }
        if (it + 1 < NIT) LOADT(it + 1);
        __syncthreads();

#pragma unroll 4
        for (int lr = 0; lr < 32; ++lr) {
            const float sl = sT[b][lr], cl = cT[b][lr];
            const float k0v = Kt[b][lr][i0], k1v = Kt[b][lr][i0 + 1];
            const float ks0 = k0v * sl, ks1 = k1v * sl;
            const float kc0 = k0v * cl, kc1 = k1v * cl;
            sk[0] += ks0; sk[1] += ks1; ck[0] += kc0; ck[1] += kc1;
            float v8[8];
            *(float4*)&v8[0] = *(float4*)&Vt[b][lr][j0];
            *(float4*)&v8[4] = *(float4*)&Vt[b][lr][j0 + 4];
#pragma unroll
            for (int jj = 0; jj < 8; ++jj) {
                S[0][jj] = fmaf(ks0, v8[jj], S[0][jj]);
                S[1][jj] = fmaf(ks1, v8[jj], S[1][jj]);
                Cc[0][jj] = fmaf(kc0, v8[jj], Cc[0][jj]);
                Cc[1][jj] = fmaf(kc1, v8[jj], Cc[1][jj]);
            }
        }
    }
#undef LOADT

    float* kvb = kvp + (size_t)c * CSTRIDE + (size_t)g * TWO_D * D_DIM;
#pragma unroll
    for (int ii = 0; ii < 2; ++ii) {
        *(float4*)&kvb[(size_t)(i0 + ii) * D_DIM + j0] =
            make_float4(S[ii][0], S[ii][1], S[ii][2], S[ii][3]);
        *(float4*)&kvb[(size_t)(i0 + ii) * D_DIM + j0 + 4] =
            make_float4(S[ii][4], S[ii][5], S[ii][6], S[ii][7]);
        *(float4*)&kvb[(size_t)(64 + i0 + ii) * D_DIM + j0] =
            make_float4(Cc[ii][0], Cc[ii][1], Cc[ii][2], Cc[ii][3]);
        *(float4*)&kvb[(size_t)(64 + i0 + ii) * D_DIM + j0 + 4] =
            make_float4(Cc[ii][4], Cc[ii][5], Cc[ii][6], Cc[ii][7]);
    }
    if (gj == 0) {
        float* ksb = kvp + (size_t)c * CSTRIDE + KV_ELEMS + (size_t)g * TWO_D;
        ksb[i0] = sk[0];
        ksb[i0 + 1] = sk[1];
        ksb[64 + i0] = ck[0];
        ksb[64 + i0 + 1] = ck[1];
    }
}

// ---------------------------------------------------------------------------
// attn via MFMA — r10 exact (verified).
// ---------------------------------------------------------------------------
__global__ __launch_bounds__(256) void attn_mfma(const float* __restrict__ Qh,
                                                 const float* __restrict__ kvp,
                                                 ushort* __restrict__ attnHi,
                                                 ushort* __restrict__ attnLo) {
    const int g = blockIdx.x;
    const int ltg = blockIdx.y;          // 0..7 (4 l-tiles of 64 each)
    const int nb = g >> 4, hh = g & 15;
    const int t = threadIdx.x;
    const int wid = t >> 6, lane = t & 63;

    __shared__ ushort kvbH[4][64][32];   // [ks][d][k'] 16 KiB
    __shared__ ushort kvbL[4][64][32];
    __shared__ ushort qaH[4][64][32];    // [ks][l][k']
    __shared__ ushort qaL[4][64][32];
    __shared__ float ksS[TWO_D];
    __shared__ float pz[64][4];
    __shared__ float zs[64];

    if (t < TWO_D) {
        const size_t o = KV_ELEMS + (size_t)g * TWO_D + t;
        ksS[t] = kvp[o] + kvp[o + CSTRIDE] + kvp[o + 2 * (size_t)CSTRIDE] +
                 kvp[o + 3 * (size_t)CSTRIDE];
    }

    {
        const float* kvg = kvp + (size_t)g * TWO_D * D_DIM;
        const int d = t & 63;
        const int igb = t >> 6;          // 0..3
        const int csd = (d >> 1) & 3;
#pragma unroll
        for (int rep = 0; rep < 4; ++rep) {
            const int i0 = (rep * 4 + igb) * 8;   // 0,8,...,120
            float v[8];
#pragma unroll
            for (int jj = 0; jj < 8; ++jj) {
                const size_t o = (size_t)(i0 + jj) * D_DIM + d;
                v[jj] = kvg[o] + kvg[o + CSTRIDE] + kvg[o + 2 * (size_t)CSTRIDE] +
                        kvg[o + 3 * (size_t)CSTRIDE];
            }
            const int ks = i0 >> 5;
            const int cs = ((((i0 >> 3) & 3) ^ csd) << 3);
            u16x8 h, l;
#pragma unroll
            for (int jj = 0; jj < 8; ++jj) {
                h[jj] = f2bf(v[jj]);
                l[jj] = f2bf(v[jj] - bf2f(h[jj]));
            }
            *(u16x8*)&kvbH[ks][d][cs] = h;
            *(u16x8*)&kvbL[ks][d][cs] = l;
        }
    }

    const int lq = t >> 2;               // 0..63 (q row)
    const int dq = (t & 3) * 16;         // d sub-block
    const int csq = (lq >> 1) & 3;

    const int lr = lane & 15, kc = lane >> 4;
    const int arow = wid * 16 + lr;
    const int aco = ((kc ^ ((arow >> 1) & 3)) << 3);
    int bro[4], bco[4];
#pragma unroll
    for (int n = 0; n < 4; ++n) {
        bro[n] = n * 16 + lr;
        bco[n] = ((kc ^ ((bro[n] >> 1) & 3)) << 3);
    }
    const int erow = (lane >> 4) * 4;
    const int ecol = lane & 15;

    __syncthreads();   // kvb + ksS ready

#pragma unroll 1
    for (int it = 0; it < 4; ++it) {
        const int lbase = (ltg * 4 + it) * 64;

        float qv[16];
        const float* qrow = Qh + ((size_t)g * L_DIM + lbase + lq) * D_DIM + dq;
        *(float4*)&qv[0] = *(const float4*)&qrow[0];
        *(float4*)&qv[4] = *(const float4*)&qrow[4];
        *(float4*)&qv[8] = *(const float4*)&qrow[8];
        *(float4*)&qv[12] = *(const float4*)&qrow[12];
        const float ang = 1.57079632679489662f * (float)(lbase + lq + 1) / (float)L_DIM;
        const float sl = sinf(ang), cl = cosf(ang);

        float p = 0.f;
#pragma unroll
        for (int jj = 0; jj < 16; ++jj)
            p += qv[jj] * (sl * ksS[dq + jj] + cl * ksS[64 + dq + jj]);
        pz[lq][t & 3] = p;

#pragma unroll
        for (int jg = 0; jg < 2; ++jg) {
            const int ib = dq + jg * 8;
            const int ks = ib >> 5;
            const int cs = ((((ib >> 3) & 3) ^ csq) << 3);
            u16x8 hs, ls, hc, lc;
#pragma unroll
            for (int jj = 0; jj < 8; ++jj) {
                const float vs = qv[jg * 8 + jj] * sl;
                const float vc = qv[jg * 8 + jj] * cl;
                hs[jj] = f2bf(vs); ls[jj] = f2bf(vs - bf2f(hs[jj]));
                hc[jj] = f2bf(vc); lc[jj] = f2bf(vc - bf2f(hc[jj]));
            }
            *(u16x8*)&qaH[ks][lq][cs] = hs;
            *(u16x8*)&qaL[ks][lq][cs] = ls;
            *(u16x8*)&qaH[ks + 2][lq][cs] = hc;
            *(u16x8*)&qaL[ks + 2][lq][cs] = lc;
        }
        __syncthreads();
        if (t < 64) {
            const float s = pz[t][0] + pz[t][1] + pz[t][2] + pz[t][3];
            zs[t] = 1.0f / fmaxf(s, 1e-6f);
        }
        __syncthreads();

        f32x4 acc[4];
        const f32x4 zv = {0.f, 0.f, 0.f, 0.f};
#pragma unroll
        for (int n = 0; n < 4; ++n) acc[n] = zv;
#pragma unroll
        for (int ks = 0; ks < 4; ++ks) {
            const bf16x8 ah = *(const bf16x8*)&qaH[ks][arow][aco];
            const bf16x8 al = *(const bf16x8*)&qaL[ks][arow][aco];
#pragma unroll
            for (int n = 0; n < 4; ++n) {
                const bf16x8 bh = *(const bf16x8*)&kvbH[ks][bro[n]][bco[n]];
                const bf16x8 bl = *(const bf16x8*)&kvbL[ks][bro[n]][bco[n]];
                acc[n] = __builtin_amdgcn_mfma_f32_16x16x32_bf16(ah, bh, acc[n], 0, 0, 0);
                acc[n] = __builtin_amdgcn_mfma_f32_16x16x32_bf16(ah, bl, acc[n], 0, 0, 0);
                acc[n] = __builtin_amdgcn_mfma_f32_16x16x32_bf16(al, bh, acc[n], 0, 0, 0);
            }
        }

#pragma unroll
        for (int n = 0; n < 4; ++n) {
#pragma unroll
            for (int q = 0; q < 4; ++q) {
                const int lrow = wid * 16 + erow + q;
                const float val = acc[n][q] * zs[lrow];
                const int d = n * 16 + ecol;
                const ushort hv = f2bf(val);
                const ushort lv = f2bf(val - bf2f(hv));
                const size_t base = (size_t)((lbase + lrow) * N_DIM + nb) * E_DIM + hh * 64 + d;
                attnHi[base] = hv;
                attnLo[base] = lv;
            }
        }
        __syncthreads();   // before next tile overwrites qa
    }
}

// ---------------------------------------------------------------------------
extern "C" void kernel_launch(void* const* d_in, const int* in_sizes, int n_in,
                              void* d_out, int out_size, void* d_ws, size_t ws_size,
                              hipStream_t stream) {
    const float* X = (const float*)d_in[0];
    const float* Wq = (const float*)d_in[1];
    const float* Wk = (const float*)d_in[2];
    const float* Wv = (const float*)d_in[3];
    const float* Wo = (const float*)d_in[4];
    float* out = (float*)d_out;

    char* ws = (char*)d_ws;
    ushort* Xhi = (ushort*)(ws + 0);            // 32 MiB (later attnHi)
    ushort* Xlo = (ushort*)(ws + 33554432);     // 32 MiB (later attnLo)
    ushort* Whi = (ushort*)(ws + 67108864);     // 4 x 2 MiB (q,k,v,o)
    ushort* Wlo = (ushort*)(ws + 75497472);     // 4 x 2 MiB
    float* kvp  = (float*)(ws + 83886080);      // CH x 4.06 MiB
    float* bufA = (float*)(ws + 100925440);     // 64 MiB (Vh)
    // peak 160.25 MiB (proven plan)

    float* Kh = out;   // d_out doubles as scratch (Kh, then Qh, then output)
    float* Vh = bufA;
    float* Qh = out;

    const size_t WMAT = (size_t)E_DIM * E_DIM;

    // all hi/lo splits in one launch
    split_all<<<2048, 256, 0, stream>>>(X, Wq, Wk, Wv, Wo, Xhi, Xlo, Whi, Wlo);

    // fused K|V projection: B = [Wk; Wv] (2048 rows) -> Kh(relu), Vh
    gemm2<2, 8><<<512, 512, 0, stream>>>(Xhi, Xlo, Whi + 1 * WMAT, Wlo + 1 * WMAT, Kh, Vh);

    // kv partials (reduced inside attn)
    kv_partial<<<dim3(NHEADS, CH), 256, 0, stream>>>(Kh, Vh, kvp);

    // Q projection (Kh dead -> reuse d_out); grid = 64 x 4 = 256
    gemm2<1, 4><<<256, 512, 0, stream>>>(Xhi, Xlo, Whi + 0 * WMAT, Wlo + 0 * WMAT, Qh, nullptr);

    // attn (MFMA) -> bf16 hi/lo into X region (X dead)
    attn_mfma<<<dim3(NHEADS, L_DIM / 256), 256, 0, stream>>>(Qh, kvp, Xhi, Xlo);

    // out = attn Wo^T; grid = 64 x 4 = 256
    gemm2<0, 4><<<256, 512, 0, stream>>>(Xhi, Xlo, Whi + 3 * WMAT, Wlo + 3 * WMAT, out, nullptr);
}